// Round 26
// baseline (297.158 us; speedup 1.0000x reference)
//
#include <hip/hip_runtime.h>
#include <hip/hip_bf16.h>
#include <math.h>

#define T_TOK 8192
#define DIM   1024
#define NEXP  8
#define FF    4096
#define BM    256
#define BN    256
#define BK    64
#define TPAD  (T_TOK + NEXP * BM)   // 10240 padded permuted rows
#define MT    (TPAD / BM)           // 40 m-tiles
#define NG1   640                   // gemm1 tiles: 16 nt x 40 mt
#define NG2   160                   // gemm2 tiles: 4 nt x 40 mt
#define NT2   4096                  // fused w2-transpose blocks (2 64x64 tiles each)
#define NRB   2048                  // router blocks in merged prep dispatch
#define NW1T  8192                  // w1-transpose tiles in merged prep dispatch

typedef __attribute__((ext_vector_type(4))) float  f32x4;
typedef __attribute__((ext_vector_type(8))) __bf16 bf16x8;
typedef __attribute__((address_space(3))) char ldschar;

// =====================================================================
// Merged prep dispatch: router (bid<NRB) + w1 transpose (bid>=NRB).
// =====================================================================
__global__ __launch_bounds__(256) void router_w1t_kernel(const float* __restrict__ x,
                              const float* __restrict__ sw, const float* __restrict__ sb,
                              int* __restrict__ route, float* __restrict__ scale,
                              __hip_bfloat16* __restrict__ xb,
                              const float* __restrict__ w1src,
                              __hip_bfloat16* __restrict__ w1tdst)
{
    __shared__ float tile[64][65];
    const int bid = blockIdx.x;

    if (bid >= NRB) {
        const int j  = bid - NRB;
        const int cx = j & 63;
        const int ry = (j >> 6) & 15;
        const int ez = j >> 10;
        const float* src = w1src + (size_t)ez * DIM * FF;
        __hip_bfloat16* dst = w1tdst + (size_t)ez * DIM * FF;
        const int c0 = cx * 64, r0 = ry * 64;
        const int t = threadIdx.x;
        const int tx = t & 15, ty = t >> 4;
#pragma unroll
        for (int i = 0; i < 4; ++i) {
            int r = ty + i * 16;
            float4 v = *(const float4*)(src + (size_t)(r0 + r) * FF + c0 + tx * 4);
            tile[r][tx * 4 + 0] = v.x; tile[r][tx * 4 + 1] = v.y;
            tile[r][tx * 4 + 2] = v.z; tile[r][tx * 4 + 3] = v.w;
        }
        __syncthreads();
        const int sx = t & 7, sy = t >> 3;
#pragma unroll
        for (int i = 0; i < 2; ++i) {
            int oc = sy + i * 32;
            bf16x8 u;
#pragma unroll
            for (int jj = 0; jj < 8; ++jj)
                u[jj] = (__bf16)tile[sx * 8 + jj][oc];
            *(bf16x8*)(dst + (size_t)(c0 + oc) * DIM + r0 + sx * 8) = u;
        }
        return;
    }

    int wave = threadIdx.x >> 6, lane = threadIdx.x & 63;
    int t = bid * 4 + wave;
    const float* xr = x + (size_t)t * DIM + lane * 16;

    float xv[16];
#pragma unroll
    for (int i = 0; i < 4; ++i)
        *(float4*)&xv[i * 4] = *(const float4*)(xr + i * 4);

    bf16x8 u0, u1;
#pragma unroll
    for (int i = 0; i < 8; ++i) { u0[i] = (__bf16)xv[i]; u1[i] = (__bf16)xv[i + 8]; }
    __hip_bfloat16* xo = xb + (size_t)t * DIM + lane * 16;
    *(bf16x8*)xo = u0;
    *(bf16x8*)(xo + 8) = u1;

    double acc[NEXP];
#pragma unroll
    for (int e = 0; e < NEXP; ++e) acc[e] = 0.0;
    const float* swp = sw + lane * 16 * NEXP;
#pragma unroll
    for (int j = 0; j < 16; ++j) {
        float4 s0 = *(const float4*)(swp + j * 8);
        float4 s1 = *(const float4*)(swp + j * 8 + 4);
        double xd = (double)xv[j];
        acc[0] += xd * (double)s0.x; acc[1] += xd * (double)s0.y;
        acc[2] += xd * (double)s0.z; acc[3] += xd * (double)s0.w;
        acc[4] += xd * (double)s1.x; acc[5] += xd * (double)s1.y;
        acc[6] += xd * (double)s1.z; acc[7] += xd * (double)s1.w;
    }
#pragma unroll
    for (int e = 0; e < NEXP; ++e) {
        double v = acc[e];
        for (int off = 32; off; off >>= 1) v += __shfl_down(v, off);
        acc[e] = v;
    }
    if (lane == 0) {
        double m = -1e300; int am = 0;
#pragma unroll
        for (int e = 0; e < NEXP; ++e) {
            double v = acc[e] + (double)sb[e];
            acc[e] = v;
            if (v > m) { m = v; am = e; }
        }
        double s = 0.0;
#pragma unroll
        for (int e = 0; e < NEXP; ++e) s += exp(acc[e] - m);
        route[t] = am;
        scale[t] = (float)(1.0 / s);
    }
}

// =====================================================================
// Single-block sort: perm-init + histogram + padded prefix + scatter.
// =====================================================================
__global__ __launch_bounds__(1024) void sort_kernel(const int* __restrict__ route,
                                                    int* __restrict__ offPad,
                                                    int* __restrict__ perm)
{
    __shared__ int c[NEXP], cur[NEXP];
    const int tid = threadIdx.x;
    if (tid < NEXP) c[tid] = 0;
    for (int i = tid; i < TPAD; i += 1024) perm[i] = -1;
    __syncthreads();
#pragma unroll
    for (int i = 0; i < T_TOK / 1024; ++i)
        atomicAdd(&c[route[tid + i * 1024]], 1);
    __syncthreads();
    if (tid == 0) {
        int o = 0;
        for (int e = 0; e < NEXP; ++e) {
            offPad[e] = o;
            cur[e] = o;
            o += ((c[e] + BM - 1) / BM) * BM;
        }
        offPad[NEXP] = o;
    }
    __syncthreads();
#pragma unroll
    for (int i = 0; i < T_TOK / 1024; ++i) {
        int t = tid + i * 1024;
        int pos = atomicAdd(&cur[route[t]], 1);
        perm[pos] = t;
    }
}

// ---------------- standalone transpose (fallback tier only) ----------------
__global__ __launch_bounds__(256) void transpose_cvt64(const float* __restrict__ src,
                                                       __hip_bfloat16* __restrict__ dst,
                                                       int R, int C)
{
    __shared__ float tile[64][65];
    size_t bofs = (size_t)blockIdx.z * (size_t)R * (size_t)C;
    int c0 = blockIdx.x * 64, r0 = blockIdx.y * 64;
    int t = threadIdx.x;
    int tx = t & 15, ty = t >> 4;
#pragma unroll
    for (int i = 0; i < 4; ++i) {
        int r = ty + i * 16;
        float4 v = *(const float4*)(src + bofs + (size_t)(r0 + r) * C + c0 + tx * 4);
        tile[r][tx * 4 + 0] = v.x; tile[r][tx * 4 + 1] = v.y;
        tile[r][tx * 4 + 2] = v.z; tile[r][tx * 4 + 3] = v.w;
    }
    __syncthreads();
    int sx = t & 7, sy = t >> 3;
#pragma unroll
    for (int i = 0; i < 2; ++i) {
        int oc = sy + i * 32;
        bf16x8 u;
#pragma unroll
        for (int j = 0; j < 8; ++j)
            u[j] = (__bf16)tile[sx * 8 + j][oc];
        *(bf16x8*)(dst + bofs + (size_t)(c0 + oc) * R + r0 + sx * 8) = u;
    }
}

// =====================================================================
// 256x256 grouped GEMM — GROUP schedule with hoisted fragment reads
// (best measured). 4 barriers / 2-K-tile iteration.
// MODE 0: h = gelu(x[perm] @ w1t^T + b1)   K=1024, N=4096  (+w2T backfill)
// MODE 1: out[perm] = (h @ w2t^T + b2)*sc  K=4096, N=1024
// =====================================================================
#define STAGE_A(b, h, t) do { \
    __builtin_amdgcn_global_load_lds((const __attribute__((address_space(1))) void*)(aSrc[h][0] + (size_t)(t) * 64), \
        (__attribute__((address_space(3))) void*)(ldsA + (b) * 32768 + (h) * 16384 + wid * 1024), 16, 0, 0); \
    __builtin_amdgcn_global_load_lds((const __attribute__((address_space(1))) void*)(aSrc[h][1] + (size_t)(t) * 64), \
        (__attribute__((address_space(3))) void*)(ldsA + (b) * 32768 + (h) * 16384 + (wid + 8) * 1024), 16, 0, 0); \
} while (0)

#define STAGE_B(b, h, t) do { \
    __builtin_amdgcn_global_load_lds((const __attribute__((address_space(1))) void*)(bSrc[h][0] + (size_t)(t) * 64), \
        (__attribute__((address_space(3))) void*)(ldsB + (b) * 32768 + (h) * 16384 + wid * 1024), 16, 0, 0); \
    __builtin_amdgcn_global_load_lds((const __attribute__((address_space(1))) void*)(bSrc[h][1] + (size_t)(t) * 64), \
        (__attribute__((address_space(3))) void*)(ldsB + (b) * 32768 + (h) * 16384 + (wid + 8) * 1024), 16, 0, 0); \
} while (0)

#define VMW asm volatile("s_waitcnt vmcnt(4)" ::: "memory")

#define LDS_FRAG(p) (*(const __attribute__((address_space(3))) bf16x8*)(p))

#define GROUP(B_, MH, LOADB, STG1, STG2, VMX) do { \
    __builtin_amdgcn_sched_barrier(0); \
    bf16x8 af0[4], af1[4]; \
    _Pragma("unroll") \
    for (int i_ = 0; i_ < 4; ++i_) { \
        af0[i_] = LDS_FRAG(aRd + (B_) * 32768 + ((MH) * 4 + i_) * 2048 + kOff[0]); \
        af1[i_] = LDS_FRAG(aRd + (B_) * 32768 + ((MH) * 4 + i_) * 2048 + kOff[1]); \
    } \
    if (LOADB) { \
        _Pragma("unroll") \
        for (int n_ = 0; n_ < 4; ++n_) { \
            bfr[0][n_] = LDS_FRAG(bRd + (B_) * 32768 + n_ * 2048 + kOff[0]); \
            bfr[1][n_] = LDS_FRAG(bRd + (B_) * 32768 + n_ * 2048 + kOff[1]); \
        } \
    } \
    STG1; STG2; \
    asm volatile("s_waitcnt lgkmcnt(0)" ::: "memory"); \
    __builtin_amdgcn_sched_barrier(0); \
    __builtin_amdgcn_s_setprio(1); \
    _Pragma("unroll") \
    for (int i_ = 0; i_ < 4; ++i_) \
        _Pragma("unroll") \
        for (int n_ = 0; n_ < 4; ++n_) \
            acc[(MH) * 4 + i_][n_] = __builtin_amdgcn_mfma_f32_16x16x32_bf16(af0[i_], bfr[0][n_], acc[(MH) * 4 + i_][n_], 0, 0, 0); \
    _Pragma("unroll") \
    for (int i_ = 0; i_ < 4; ++i_) \
        _Pragma("unroll") \
        for (int n_ = 0; n_ < 4; ++n_) \
            acc[(MH) * 4 + i_][n_] = __builtin_amdgcn_mfma_f32_16x16x32_bf16(af1[i_], bfr[1][n_], acc[(MH) * 4 + i_][n_], 0, 0, 0); \
    __builtin_amdgcn_s_setprio(0); \
    VMX; \
    __builtin_amdgcn_s_barrier(); \
} while (0)

template<int MODE>
__global__ __launch_bounds__(512, 2) void moe_gemm8(
    const __hip_bfloat16* __restrict__ A,
    const __hip_bfloat16* __restrict__ Bw,    // [E][N][K]
    const float* __restrict__ bias,           // [E][N]
    const int* __restrict__ offPad,
    const int* __restrict__ perm,
    const float* __restrict__ scale,
    __hip_bfloat16* __restrict__ Hout,
    float* __restrict__ Out,
    const float* __restrict__ w2src,          // MODE 0 fused transpose src [E][F][D]
    __hip_bfloat16* __restrict__ w2tdst,      // MODE 0 fused transpose dst [E][D][F]
    const int K, const int N)
{
    __shared__ char lds[131072];
    const int tid = threadIdx.x;
    const int bid = blockIdx.x;

    if (MODE == 0 && bid >= NG1) {
        // ---- fused w2 transpose: 2 independent 64x64 tiles per block ----
        const int j    = bid - NG1;
        const int t2   = tid & 255;
        const int half = tid >> 8;
        const int tile_id = j * 2 + half;
        const int cx = tile_id & 15;
        const int ry = (tile_id >> 4) & 63;
        const int ez = tile_id >> 10;
        float (*tl)[65] = (float (*)[65])(lds + half * 17408);
        const float* src = w2src + (size_t)ez * FF * DIM;
        __hip_bfloat16* dst = w2tdst + (size_t)ez * DIM * FF;
        const int c0 = cx * 64, r0 = ry * 64;
        const int tx = t2 & 15, ty = t2 >> 4;
#pragma unroll
        for (int i = 0; i < 4; ++i) {
            int r = ty + i * 16;
            float4 v = *(const float4*)(src + (size_t)(r0 + r) * DIM + c0 + tx * 4);
            tl[r][tx * 4 + 0] = v.x; tl[r][tx * 4 + 1] = v.y;
            tl[r][tx * 4 + 2] = v.z; tl[r][tx * 4 + 3] = v.w;
        }
        __syncthreads();
        const int sx = t2 & 7, sy = t2 >> 3;
#pragma unroll
        for (int i = 0; i < 2; ++i) {
            int oc = sy + i * 32;
            bf16x8 u;
#pragma unroll
            for (int jj = 0; jj < 8; ++jj)
                u[jj] = (__bf16)tl[sx * 8 + jj][oc];
            *(bf16x8*)(dst + (size_t)(c0 + oc) * FF + r0 + sx * 8) = u;
        }
        return;
    }

    // Block -> tile mapping (round-8: mt-fastest for g1, mt-grouped for g2).
    int mt, nt;
    if (MODE == 0) {
        const int swz = (bid & 7) * (NG1 >> 3) + (bid >> 3);
        mt = swz % MT;
        nt = swz / MT;
    } else {
        mt = (bid & 7) + 8 * (bid >> 5);
        nt = (bid >> 3) & 3;
    }
    const int m0 = mt * BM;
    if (m0 >= offPad[NEXP]) return;
    int e = 0;
    while (offPad[e + 1] <= m0) ++e;

    ldschar* ldsA = (ldschar*)lds;               // [2 buf][2 half][128 rows][128 B]
    ldschar* ldsB = (ldschar*)(lds + 65536);

    const int lane = tid & 63;
    const int wid  = tid >> 6;      // 0..7
    const int wr   = wid >> 2;      // 0..1  (M half)
    const int wc   = wid & 3;       // 0..3  (N quarter)
    const int g    = lane >> 4, rl = lane & 15;

    const __hip_bfloat16* Bp = Bw + (size_t)e * (size_t)N * (size_t)K;

    const int l3 = lane >> 3;
    const int colOff = ((lane & 7) ^ l3) * 8;
    const __hip_bfloat16* aSrc[2][2];
    const __hip_bfloat16* bSrc[2][2];
#pragma unroll
    for (int h = 0; h < 2; ++h)
#pragma unroll
        for (int j = 0; j < 2; ++j) {
            int r = (wid + j * 8) * 8 + l3;
            int arow = m0 + h * 128 + r;
            size_t ar;
            if (MODE == 0) { int tk = perm[arow]; ar = (size_t)(tk < 0 ? 0 : tk); }
            else           { ar = (size_t)arow; }
            aSrc[h][j] = A + ar * (size_t)K + colOff;
            bSrc[h][j] = Bp + (size_t)(nt * BN + h * 128 + r) * (size_t)K + colOff;
        }

    const ldschar* aRd = ldsA + wr * 16384 + rl * 128;
    const ldschar* bRd = ldsB + (wc >> 1) * 16384 + (wc & 1) * 8192 + rl * 128;
    int kOff[2];
    kOff[0] = ((0 * 4 + g) ^ (rl & 7)) * 16;
    kOff[1] = ((1 * 4 + g) ^ (rl & 7)) * 16;

    f32x4 acc[8][4];
#pragma unroll
    for (int i = 0; i < 8; ++i)
#pragma unroll
        for (int n = 0; n < 4; ++n) acc[i][n] = (f32x4)0.0f;
    bf16x8 bfr[2][4];

    const int ntiles = K >> 6;

    STAGE_A(0, 0, 0); STAGE_A(0, 1, 0);
    STAGE_B(0, 0, 0); STAGE_B(0, 1, 0);
    STAGE_B(1, 0, 1); STAGE_B(1, 1, 1);
    asm volatile("s_waitcnt vmcnt(4)" ::: "memory");
    __builtin_amdgcn_s_barrier();

    for (int it = 0; it < (ntiles >> 1); ++it) {
        const int t1 = 2 * it + 1;
        const int t2 = 2 * it + 2 < ntiles ? 2 * it + 2 : ntiles - 1;
        const int t3 = 2 * it + 3 < ntiles ? 2 * it + 3 : ntiles - 1;
        GROUP(0, 0, true,  STAGE_A(1, 0, t1), STAGE_A(1, 1, t1), );
        GROUP(0, 1, false, STAGE_B(0, 0, t2), STAGE_B(0, 1, t2), VMW);
        GROUP(1, 0, true,  STAGE_A(0, 0, t2), STAGE_A(0, 1, t2), );
        GROUP(1, 1, false, STAGE_B(1, 0, t3), STAGE_B(1, 1, t3), VMW);
    }
    asm volatile("s_waitcnt vmcnt(0)" ::: "memory");

    const int colBase = nt * BN + wc * 64;
    const int rowBase = m0 + wr * 128;
    float bcol[4];
#pragma unroll
    for (int n = 0; n < 4; ++n) bcol[n] = bias[(size_t)e * N + colBase + n * 16 + rl];

    if (MODE == 0) {
#pragma unroll
        for (int m = 0; m < 8; ++m) {
#pragma unroll
            for (int r = 0; r < 4; ++r) {
                int row = rowBase + m * 16 + g * 4 + r;
                __hip_bfloat16* hrow = Hout + (size_t)row * N + colBase;
#pragma unroll
                for (int n = 0; n < 4; ++n) {
                    float v = acc[m][n][r] + bcol[n];
                    float u = -1.5957691216057308f * (v + 0.044715f * v * v * v);
                    float gel = v / (1.f + __expf(u));
                    hrow[n * 16 + rl] = __float2bfloat16(gel);
                }
            }
        }
    } else {
#pragma unroll
        for (int m = 0; m < 8; ++m) {
#pragma unroll
            for (int r = 0; r < 4; ++r) {
                int row = rowBase + m * 16 + g * 4 + r;
                int tk = perm[row];
                if (tk >= 0) {
                    float sc = scale[tk];
                    float* orow = Out + (size_t)tk * N + colBase;
#pragma unroll
                    for (int n = 0; n < 4; ++n)
                        orow[n * 16 + rl] = (acc[m][n][r] + bcol[n]) * sc;
                }
            }
        }
    }
}

extern "C" void kernel_launch(void* const* d_in, const int* in_sizes, int n_in,
                              void* d_out, int out_size, void* d_ws, size_t ws_size,
                              hipStream_t stream)
{
    const float* x  = (const float*)d_in[0];
    const float* sw = (const float*)d_in[1];
    const float* sb = (const float*)d_in[2];
    const float* w1 = (const float*)d_in[3];
    const float* b1 = (const float*)d_in[4];
    const float* w2 = (const float*)d_in[5];
    const float* b2 = (const float*)d_in[6];
    float* out = (float*)d_out;
    char* ws = (char*)d_ws;

    int*   offPad = (int*)(ws + 3072);
    int*   route  = (int*)(ws + 4096);
    float* scale  = (float*)(ws + 36864);
    int*   perm   = (int*)(ws + 69632);

    const size_t offXb   = 131072;
    const size_t szXb    = (size_t)T_TOK * DIM * 2;       // 16.8 MB
    const size_t offW1   = offXb + szXb;                  // 16,908,288
    const size_t szW     = (size_t)NEXP * DIM * FF * 2;   // 67.1 MB
    const size_t offW2   = offW1 + szW;                   // 84,017,152
    const size_t szH     = (size_t)TPAD * FF * 2;         // 83.9 MB
    const size_t offHF   = offW2 + szW;                   // 151,126,016 (fused tier)
    const size_t needF   = offHF + szH;                   // ~235.0 MB

    const bool fuseT = ws_size >= needF;

    __hip_bfloat16* xb  = (__hip_bfloat16*)(ws + offXb);
    __hip_bfloat16* w1t = (__hip_bfloat16*)(ws + offW1);
    __hip_bfloat16* w2t = (__hip_bfloat16*)(ws + (fuseT ? offW2 : offW1)); // fallback aliases w1t
    __hip_bfloat16* h   = (__hip_bfloat16*)(ws + (fuseT ? offHF : offW2));

    router_w1t_kernel<<<NRB + NW1T, 256, 0, stream>>>(x, sw, sb, route, scale, xb, w1, w1t);
    sort_kernel<<<1, 1024, 0, stream>>>(route, offPad, perm);

    if (fuseT) {
        moe_gemm8<0><<<NG1 + NT2, 512, 0, stream>>>(
            xb, w1t, b1, offPad, perm, scale, h, nullptr, w2, w2t, DIM, FF);
        moe_gemm8<1><<<NG2, 512, 0, stream>>>(
            h, w2t, b2, offPad, perm, scale, nullptr, out, nullptr, nullptr, FF, DIM);
    } else {
        moe_gemm8<0><<<NG1, 512, 0, stream>>>(
            xb, w1t, b1, offPad, perm, scale, h, nullptr, nullptr, nullptr, DIM, FF);
        transpose_cvt64<<<dim3(DIM / 64, FF / 64, NEXP), 256, 0, stream>>>(w2, w2t, FF, DIM);
        moe_gemm8<1><<<NG2, 512, 0, stream>>>(
            h, w2t, b2, offPad, perm, scale, nullptr, out, nullptr, nullptr, FF, DIM);
    }
}

// Round 27
// 297.095 us; speedup vs baseline: 1.0002x; 1.0002x over previous
//
#include <hip/hip_runtime.h>
#include <hip/hip_bf16.h>
#include <math.h>

#define T_TOK 8192
#define DIM   1024
#define NEXP  8
#define FF    4096
#define BM    256
#define BN    256
#define BK    64
#define TPAD  (T_TOK + NEXP * BM)   // 10240 padded permuted rows
#define MT    (TPAD / BM)           // 40 m-tiles
#define NG1   640                   // gemm1 tiles: 16 nt x 40 mt
#define NG2   160                   // gemm2 tiles: 4 nt x 40 mt
#define NT2   4096                  // fused w2-transpose blocks (2 64x64 tiles each)
#define NRB   2048                  // router blocks in merged prep dispatch
#define NW1T  8192                  // w1-transpose tiles in merged prep dispatch

typedef __attribute__((ext_vector_type(4))) float  f32x4;
typedef __attribute__((ext_vector_type(8))) __bf16 bf16x8;
typedef __attribute__((address_space(3))) char ldschar;

// =====================================================================
// Merged prep dispatch: router (bid<NRB) + w1 transpose (bid>=NRB).
// =====================================================================
__global__ __launch_bounds__(256) void router_w1t_kernel(const float* __restrict__ x,
                              const float* __restrict__ sw, const float* __restrict__ sb,
                              int* __restrict__ route, float* __restrict__ scale,
                              __hip_bfloat16* __restrict__ xb,
                              const float* __restrict__ w1src,
                              __hip_bfloat16* __restrict__ w1tdst)
{
    __shared__ float tile[64][65];
    const int bid = blockIdx.x;

    if (bid >= NRB) {
        const int j  = bid - NRB;
        const int cx = j & 63;
        const int ry = (j >> 6) & 15;
        const int ez = j >> 10;
        const float* src = w1src + (size_t)ez * DIM * FF;
        __hip_bfloat16* dst = w1tdst + (size_t)ez * DIM * FF;
        const int c0 = cx * 64, r0 = ry * 64;
        const int t = threadIdx.x;
        const int tx = t & 15, ty = t >> 4;
#pragma unroll
        for (int i = 0; i < 4; ++i) {
            int r = ty + i * 16;
            float4 v = *(const float4*)(src + (size_t)(r0 + r) * FF + c0 + tx * 4);
            tile[r][tx * 4 + 0] = v.x; tile[r][tx * 4 + 1] = v.y;
            tile[r][tx * 4 + 2] = v.z; tile[r][tx * 4 + 3] = v.w;
        }
        __syncthreads();
        const int sx = t & 7, sy = t >> 3;
#pragma unroll
        for (int i = 0; i < 2; ++i) {
            int oc = sy + i * 32;
            bf16x8 u;
#pragma unroll
            for (int jj = 0; jj < 8; ++jj)
                u[jj] = (__bf16)tile[sx * 8 + jj][oc];
            *(bf16x8*)(dst + (size_t)(c0 + oc) * DIM + r0 + sx * 8) = u;
        }
        return;
    }

    int wave = threadIdx.x >> 6, lane = threadIdx.x & 63;
    int t = bid * 4 + wave;
    const float* xr = x + (size_t)t * DIM + lane * 16;

    float xv[16];
#pragma unroll
    for (int i = 0; i < 4; ++i)
        *(float4*)&xv[i * 4] = *(const float4*)(xr + i * 4);

    bf16x8 u0, u1;
#pragma unroll
    for (int i = 0; i < 8; ++i) { u0[i] = (__bf16)xv[i]; u1[i] = (__bf16)xv[i + 8]; }
    __hip_bfloat16* xo = xb + (size_t)t * DIM + lane * 16;
    *(bf16x8*)xo = u0;
    *(bf16x8*)(xo + 8) = u1;

    double acc[NEXP];
#pragma unroll
    for (int e = 0; e < NEXP; ++e) acc[e] = 0.0;
    const float* swp = sw + lane * 16 * NEXP;
#pragma unroll
    for (int j = 0; j < 16; ++j) {
        float4 s0 = *(const float4*)(swp + j * 8);
        float4 s1 = *(const float4*)(swp + j * 8 + 4);
        double xd = (double)xv[j];
        acc[0] += xd * (double)s0.x; acc[1] += xd * (double)s0.y;
        acc[2] += xd * (double)s0.z; acc[3] += xd * (double)s0.w;
        acc[4] += xd * (double)s1.x; acc[5] += xd * (double)s1.y;
        acc[6] += xd * (double)s1.z; acc[7] += xd * (double)s1.w;
    }
#pragma unroll
    for (int e = 0; e < NEXP; ++e) {
        double v = acc[e];
        for (int off = 32; off; off >>= 1) v += __shfl_down(v, off);
        acc[e] = v;
    }
    if (lane == 0) {
        double m = -1e300; int am = 0;
#pragma unroll
        for (int e = 0; e < NEXP; ++e) {
            double v = acc[e] + (double)sb[e];
            acc[e] = v;
            if (v > m) { m = v; am = e; }
        }
        double s = 0.0;
#pragma unroll
        for (int e = 0; e < NEXP; ++e) s += exp(acc[e] - m);
        route[t] = am;
        scale[t] = (float)(1.0 / s);
    }
}

// =====================================================================
// Single-block sort: perm-init + histogram + padded prefix + scatter.
// =====================================================================
__global__ __launch_bounds__(1024) void sort_kernel(const int* __restrict__ route,
                                                    int* __restrict__ offPad,
                                                    int* __restrict__ perm)
{
    __shared__ int c[NEXP], cur[NEXP];
    const int tid = threadIdx.x;
    if (tid < NEXP) c[tid] = 0;
    for (int i = tid; i < TPAD; i += 1024) perm[i] = -1;
    __syncthreads();
#pragma unroll
    for (int i = 0; i < T_TOK / 1024; ++i)
        atomicAdd(&c[route[tid + i * 1024]], 1);
    __syncthreads();
    if (tid == 0) {
        int o = 0;
        for (int e = 0; e < NEXP; ++e) {
            offPad[e] = o;
            cur[e] = o;
            o += ((c[e] + BM - 1) / BM) * BM;
        }
        offPad[NEXP] = o;
    }
    __syncthreads();
#pragma unroll
    for (int i = 0; i < T_TOK / 1024; ++i) {
        int t = tid + i * 1024;
        int pos = atomicAdd(&cur[route[t]], 1);
        perm[pos] = t;
    }
}

// ---------------- standalone transpose (fallback tier only) ----------------
__global__ __launch_bounds__(256) void transpose_cvt64(const float* __restrict__ src,
                                                       __hip_bfloat16* __restrict__ dst,
                                                       int R, int C)
{
    __shared__ float tile[64][65];
    size_t bofs = (size_t)blockIdx.z * (size_t)R * (size_t)C;
    int c0 = blockIdx.x * 64, r0 = blockIdx.y * 64;
    int t = threadIdx.x;
    int tx = t & 15, ty = t >> 4;
#pragma unroll
    for (int i = 0; i < 4; ++i) {
        int r = ty + i * 16;
        float4 v = *(const float4*)(src + bofs + (size_t)(r0 + r) * C + c0 + tx * 4);
        tile[r][tx * 4 + 0] = v.x; tile[r][tx * 4 + 1] = v.y;
        tile[r][tx * 4 + 2] = v.z; tile[r][tx * 4 + 3] = v.w;
    }
    __syncthreads();
    int sx = t & 7, sy = t >> 3;
#pragma unroll
    for (int i = 0; i < 2; ++i) {
        int oc = sy + i * 32;
        bf16x8 u;
#pragma unroll
        for (int j = 0; j < 8; ++j)
            u[j] = (__bf16)tile[sx * 8 + j][oc];
        *(bf16x8*)(dst + bofs + (size_t)(c0 + oc) * R + r0 + sx * 8) = u;
    }
}

// =====================================================================
// 256x256 grouped GEMM — GROUP schedule with hoisted fragment reads
// (best measured). 4 barriers / 2-K-tile iteration.
// MODE 0: h = gelu(x[perm] @ w1t^T + b1)   K=1024, N=4096  (+w2T backfill)
// MODE 1: out[perm] = (h @ w2t^T + b2)*sc  K=4096, N=1024
// =====================================================================
#define STAGE_A(b, h, t) do { \
    __builtin_amdgcn_global_load_lds((const __attribute__((address_space(1))) void*)(aSrc[h][0] + (size_t)(t) * 64), \
        (__attribute__((address_space(3))) void*)(ldsA + (b) * 32768 + (h) * 16384 + wid * 1024), 16, 0, 0); \
    __builtin_amdgcn_global_load_lds((const __attribute__((address_space(1))) void*)(aSrc[h][1] + (size_t)(t) * 64), \
        (__attribute__((address_space(3))) void*)(ldsA + (b) * 32768 + (h) * 16384 + (wid + 8) * 1024), 16, 0, 0); \
} while (0)

#define STAGE_B(b, h, t) do { \
    __builtin_amdgcn_global_load_lds((const __attribute__((address_space(1))) void*)(bSrc[h][0] + (size_t)(t) * 64), \
        (__attribute__((address_space(3))) void*)(ldsB + (b) * 32768 + (h) * 16384 + wid * 1024), 16, 0, 0); \
    __builtin_amdgcn_global_load_lds((const __attribute__((address_space(1))) void*)(bSrc[h][1] + (size_t)(t) * 64), \
        (__attribute__((address_space(3))) void*)(ldsB + (b) * 32768 + (h) * 16384 + (wid + 8) * 1024), 16, 0, 0); \
} while (0)

#define VMW asm volatile("s_waitcnt vmcnt(4)" ::: "memory")

#define LDS_FRAG(p) (*(const __attribute__((address_space(3))) bf16x8*)(p))

#define GROUP(B_, MH, LOADB, STG1, STG2, VMX) do { \
    __builtin_amdgcn_sched_barrier(0); \
    bf16x8 af0[4], af1[4]; \
    _Pragma("unroll") \
    for (int i_ = 0; i_ < 4; ++i_) { \
        af0[i_] = LDS_FRAG(aRd + (B_) * 32768 + ((MH) * 4 + i_) * 2048 + kOff[0]); \
        af1[i_] = LDS_FRAG(aRd + (B_) * 32768 + ((MH) * 4 + i_) * 2048 + kOff[1]); \
    } \
    if (LOADB) { \
        _Pragma("unroll") \
        for (int n_ = 0; n_ < 4; ++n_) { \
            bfr[0][n_] = LDS_FRAG(bRd + (B_) * 32768 + n_ * 2048 + kOff[0]); \
            bfr[1][n_] = LDS_FRAG(bRd + (B_) * 32768 + n_ * 2048 + kOff[1]); \
        } \
    } \
    STG1; STG2; \
    asm volatile("s_waitcnt lgkmcnt(0)" ::: "memory"); \
    __builtin_amdgcn_sched_barrier(0); \
    __builtin_amdgcn_s_setprio(1); \
    _Pragma("unroll") \
    for (int i_ = 0; i_ < 4; ++i_) \
        _Pragma("unroll") \
        for (int n_ = 0; n_ < 4; ++n_) \
            acc[(MH) * 4 + i_][n_] = __builtin_amdgcn_mfma_f32_16x16x32_bf16(af0[i_], bfr[0][n_], acc[(MH) * 4 + i_][n_], 0, 0, 0); \
    _Pragma("unroll") \
    for (int i_ = 0; i_ < 4; ++i_) \
        _Pragma("unroll") \
        for (int n_ = 0; n_ < 4; ++n_) \
            acc[(MH) * 4 + i_][n_] = __builtin_amdgcn_mfma_f32_16x16x32_bf16(af1[i_], bfr[1][n_], acc[(MH) * 4 + i_][n_], 0, 0, 0); \
    __builtin_amdgcn_s_setprio(0); \
    VMX; \
    __builtin_amdgcn_s_barrier(); \
} while (0)

template<int MODE>
__global__ __launch_bounds__(512, 2) void moe_gemm8(
    const __hip_bfloat16* __restrict__ A,
    const __hip_bfloat16* __restrict__ Bw,    // [E][N][K]
    const float* __restrict__ bias,           // [E][N]
    const int* __restrict__ offPad,
    const int* __restrict__ perm,
    const float* __restrict__ scale,
    __hip_bfloat16* __restrict__ Hout,
    float* __restrict__ Out,
    const float* __restrict__ w2src,          // MODE 0 fused transpose src [E][F][D]
    __hip_bfloat16* __restrict__ w2tdst,      // MODE 0 fused transpose dst [E][D][F]
    const int K, const int N)
{
    __shared__ char lds[131072];
    const int tid = threadIdx.x;
    const int bid = blockIdx.x;

    if (MODE == 0 && bid >= NG1) {
        // ---- fused w2 transpose: 2 independent 64x64 tiles per block ----
        const int j    = bid - NG1;
        const int t2   = tid & 255;
        const int half = tid >> 8;
        const int tile_id = j * 2 + half;
        const int cx = tile_id & 15;
        const int ry = (tile_id >> 4) & 63;
        const int ez = tile_id >> 10;
        float (*tl)[65] = (float (*)[65])(lds + half * 17408);
        const float* src = w2src + (size_t)ez * FF * DIM;
        __hip_bfloat16* dst = w2tdst + (size_t)ez * DIM * FF;
        const int c0 = cx * 64, r0 = ry * 64;
        const int tx = t2 & 15, ty = t2 >> 4;
#pragma unroll
        for (int i = 0; i < 4; ++i) {
            int r = ty + i * 16;
            float4 v = *(const float4*)(src + (size_t)(r0 + r) * DIM + c0 + tx * 4);
            tl[r][tx * 4 + 0] = v.x; tl[r][tx * 4 + 1] = v.y;
            tl[r][tx * 4 + 2] = v.z; tl[r][tx * 4 + 3] = v.w;
        }
        __syncthreads();
        const int sx = t2 & 7, sy = t2 >> 3;
#pragma unroll
        for (int i = 0; i < 2; ++i) {
            int oc = sy + i * 32;
            bf16x8 u;
#pragma unroll
            for (int jj = 0; jj < 8; ++jj)
                u[jj] = (__bf16)tl[sx * 8 + jj][oc];
            *(bf16x8*)(dst + (size_t)(c0 + oc) * FF + r0 + sx * 8) = u;
        }
        return;
    }

    // Block -> tile mapping (round-8: mt-fastest for g1, mt-grouped for g2).
    int mt, nt;
    if (MODE == 0) {
        const int swz = (bid & 7) * (NG1 >> 3) + (bid >> 3);
        mt = swz % MT;
        nt = swz / MT;
    } else {
        mt = (bid & 7) + 8 * (bid >> 5);
        nt = (bid >> 3) & 3;
    }
    const int m0 = mt * BM;
    if (m0 >= offPad[NEXP]) return;
    int e = 0;
    while (offPad[e + 1] <= m0) ++e;

    ldschar* ldsA = (ldschar*)lds;               // [2 buf][2 half][128 rows][128 B]
    ldschar* ldsB = (ldschar*)(lds + 65536);

    const int lane = tid & 63;
    const int wid  = tid >> 6;      // 0..7
    const int wr   = wid >> 2;      // 0..1  (M half)
    const int wc   = wid & 3;       // 0..3  (N quarter)
    const int g    = lane >> 4, rl = lane & 15;

    const __hip_bfloat16* Bp = Bw + (size_t)e * (size_t)N * (size_t)K;

    const int l3 = lane >> 3;
    const int colOff = ((lane & 7) ^ l3) * 8;
    const __hip_bfloat16* aSrc[2][2];
    const __hip_bfloat16* bSrc[2][2];
#pragma unroll
    for (int h = 0; h < 2; ++h)
#pragma unroll
        for (int j = 0; j < 2; ++j) {
            int r = (wid + j * 8) * 8 + l3;
            int arow = m0 + h * 128 + r;
            size_t ar;
            if (MODE == 0) { int tk = perm[arow]; ar = (size_t)(tk < 0 ? 0 : tk); }
            else           { ar = (size_t)arow; }
            aSrc[h][j] = A + ar * (size_t)K + colOff;
            bSrc[h][j] = Bp + (size_t)(nt * BN + h * 128 + r) * (size_t)K + colOff;
        }

    const ldschar* aRd = ldsA + wr * 16384 + rl * 128;
    const ldschar* bRd = ldsB + (wc >> 1) * 16384 + (wc & 1) * 8192 + rl * 128;
    int kOff[2];
    kOff[0] = ((0 * 4 + g) ^ (rl & 7)) * 16;
    kOff[1] = ((1 * 4 + g) ^ (rl & 7)) * 16;

    f32x4 acc[8][4];
#pragma unroll
    for (int i = 0; i < 8; ++i)
#pragma unroll
        for (int n = 0; n < 4; ++n) acc[i][n] = (f32x4)0.0f;
    bf16x8 bfr[2][4];

    const int ntiles = K >> 6;

    STAGE_A(0, 0, 0); STAGE_A(0, 1, 0);
    STAGE_B(0, 0, 0); STAGE_B(0, 1, 0);
    STAGE_B(1, 0, 1); STAGE_B(1, 1, 1);
    asm volatile("s_waitcnt vmcnt(4)" ::: "memory");
    __builtin_amdgcn_s_barrier();

    for (int it = 0; it < (ntiles >> 1); ++it) {
        const int t1 = 2 * it + 1;
        const int t2 = 2 * it + 2 < ntiles ? 2 * it + 2 : ntiles - 1;
        const int t3 = 2 * it + 3 < ntiles ? 2 * it + 3 : ntiles - 1;
        GROUP(0, 0, true,  STAGE_A(1, 0, t1), STAGE_A(1, 1, t1), );
        GROUP(0, 1, false, STAGE_B(0, 0, t2), STAGE_B(0, 1, t2), VMW);
        GROUP(1, 0, true,  STAGE_A(0, 0, t2), STAGE_A(0, 1, t2), );
        GROUP(1, 1, false, STAGE_B(1, 0, t3), STAGE_B(1, 1, t3), VMW);
    }
    asm volatile("s_waitcnt vmcnt(0)" ::: "memory");

    const int colBase = nt * BN + wc * 64;
    const int rowBase = m0 + wr * 128;
    float bcol[4];
#pragma unroll
    for (int n = 0; n < 4; ++n) bcol[n] = bias[(size_t)e * N + colBase + n * 16 + rl];

    if (MODE == 0) {
#pragma unroll
        for (int m = 0; m < 8; ++m) {
#pragma unroll
            for (int r = 0; r < 4; ++r) {
                int row = rowBase + m * 16 + g * 4 + r;
                __hip_bfloat16* hrow = Hout + (size_t)row * N + colBase;
#pragma unroll
                for (int n = 0; n < 4; ++n) {
                    float v = acc[m][n][r] + bcol[n];
                    float u = -1.5957691216057308f * (v + 0.044715f * v * v * v);
                    float gel = v / (1.f + __expf(u));
                    hrow[n * 16 + rl] = __float2bfloat16(gel);
                }
            }
        }
    } else {
#pragma unroll
        for (int m = 0; m < 8; ++m) {
#pragma unroll
            for (int r = 0; r < 4; ++r) {
                int row = rowBase + m * 16 + g * 4 + r;
                int tk = perm[row];
                if (tk >= 0) {
                    float sc = scale[tk];
                    float* orow = Out + (size_t)tk * N + colBase;
#pragma unroll
                    for (int n = 0; n < 4; ++n)
                        orow[n * 16 + rl] = (acc[m][n][r] + bcol[n]) * sc;
                }
            }
        }
    }
}

extern "C" void kernel_launch(void* const* d_in, const int* in_sizes, int n_in,
                              void* d_out, int out_size, void* d_ws, size_t ws_size,
                              hipStream_t stream)
{
    const float* x  = (const float*)d_in[0];
    const float* sw = (const float*)d_in[1];
    const float* sb = (const float*)d_in[2];
    const float* w1 = (const float*)d_in[3];
    const float* b1 = (const float*)d_in[4];
    const float* w2 = (const float*)d_in[5];
    const float* b2 = (const float*)d_in[6];
    float* out = (float*)d_out;
    char* ws = (char*)d_ws;

    int*   offPad = (int*)(ws + 3072);
    int*   route  = (int*)(ws + 4096);
    float* scale  = (float*)(ws + 36864);
    int*   perm   = (int*)(ws + 69632);

    const size_t offXb   = 131072;
    const size_t szXb    = (size_t)T_TOK * DIM * 2;       // 16.8 MB
    const size_t offW1   = offXb + szXb;                  // 16,908,288
    const size_t szW     = (size_t)NEXP * DIM * FF * 2;   // 67.1 MB
    const size_t offW2   = offW1 + szW;                   // 84,017,152
    const size_t szH     = (size_t)TPAD * FF * 2;         // 83.9 MB
    const size_t offHF   = offW2 + szW;                   // 151,126,016 (fused tier)
    const size_t needF   = offHF + szH;                   // ~235.0 MB

    const bool fuseT = ws_size >= needF;

    __hip_bfloat16* xb  = (__hip_bfloat16*)(ws + offXb);
    __hip_bfloat16* w1t = (__hip_bfloat16*)(ws + offW1);
    __hip_bfloat16* w2t = (__hip_bfloat16*)(ws + (fuseT ? offW2 : offW1)); // fallback aliases w1t
    __hip_bfloat16* h   = (__hip_bfloat16*)(ws + (fuseT ? offHF : offW2));

    router_w1t_kernel<<<NRB + NW1T, 256, 0, stream>>>(x, sw, sb, route, scale, xb, w1, w1t);
    sort_kernel<<<1, 1024, 0, stream>>>(route, offPad, perm);

    if (fuseT) {
        moe_gemm8<0><<<NG1 + NT2, 512, 0, stream>>>(
            xb, w1t, b1, offPad, perm, scale, h, nullptr, w2, w2t, DIM, FF);
        moe_gemm8<1><<<NG2, 512, 0, stream>>>(
            h, w2t, b2, offPad, perm, scale, nullptr, out, nullptr, nullptr, FF, DIM);
    } else {
        moe_gemm8<0><<<NG1, 512, 0, stream>>>(
            xb, w1t, b1, offPad, perm, scale, h, nullptr, nullptr, nullptr, DIM, FF);
        transpose_cvt64<<<dim3(DIM / 64, FF / 64, NEXP), 256, 0, stream>>>(w2, w2t, FF, DIM);
        moe_gemm8<1><<<NG2, 512, 0, stream>>>(
            h, w2t, b2, offPad, perm, scale, nullptr, out, nullptr, nullptr, FF, DIM);
    }
}